// Round 15
// baseline (183.246 us; speedup 1.0000x reference)
//
#include <hip/hip_runtime.h>

// DIAGNOSTIC ROUND: R12 kernel with REP=4 internal work repetition so the
// main dispatch (~240us) beats the harness's ~155us poison-fills into the
// rocprof top-5 and we finally see its VALUBusy/hbm/FETCH_SIZE/occupancy.
// chunk = cur & MASK; all writes are idempotent (same values) -> determinism.
#define REPS 4

static __device__ __forceinline__ unsigned umax2(unsigned a, unsigned b) { return a > b ? a : b; }

static __device__ __forceinline__ float qb(float v, int sel) {
    int i = __float_as_int(v), r;
    switch (sel) {
        case 0:  r = __builtin_amdgcn_update_dpp(0, i, 0x00, 0xF, 0xF, true); break;
        case 1:  r = __builtin_amdgcn_update_dpp(0, i, 0x55, 0xF, 0xF, true); break;
        case 2:  r = __builtin_amdgcn_update_dpp(0, i, 0xAA, 0xF, 0xF, true); break;
        default: r = __builtin_amdgcn_update_dpp(0, i, 0xFF, 0xF, 0xF, true); break;
    }
    return __int_as_float(r);
}

static __device__ __forceinline__ int mbcnt64(unsigned long long m, int acc) {
    acc = __builtin_amdgcn_mbcnt_lo((unsigned)m, acc);
    acc = __builtin_amdgcn_mbcnt_hi((unsigned)(m >> 32), acc);
    return acc;
}

__global__ __launch_bounds__(256) void slater_det_main(
    const float* __restrict__ cfg,
    const float* __restrict__ sup,
    const float* __restrict__ sdn,
    float* __restrict__ out,
    unsigned* __restrict__ ws_count,
    unsigned* __restrict__ ws_rec,
    unsigned cap,
    int total, int mask)
{
    __shared__ __align__(16) int idx_lds[4][16][16];

    const int tid  = threadIdx.x;
    const int wave = tid >> 6;
    const int lane = tid & 63;
    const int wgid = blockIdx.x * 4 + wave;
    const int nw   = gridDim.x * 4;

    const int g = lane >> 2;
    const int q = lane & 3;
    const float* tab = (g & 1) ? sdn : sup;

    float4 c[8];
    int cur = wgid;
    if (cur >= total) return;
    int chunk = cur & mask;

#pragma unroll
    for (int d = 0; d < 8; ++d)
        c[d] = *(const float4*)(cfg + (size_t)chunk * 4096 + (size_t)d * 256 + (size_t)lane * 4);

    while (cur < total) {
        const int nxt = cur + nw;
        const int chnxt = nxt & mask;

#pragma unroll
        for (int d = 0; d < 8; ++d) {
            float4 v = c[d];
            bool n0 = v.x != 0.f, n1 = v.y != 0.f, n2 = v.z != 0.f, n3 = v.w != 0.f;
            unsigned long long b0 = __ballot(n0);
            unsigned long long b1 = __ballot(n1);
            unsigned long long b2 = __ballot(n2);
            unsigned long long b3 = __ballot(n3);
            int r = mbcnt64(b3, mbcnt64(b2, mbcnt64(b1, mbcnt64(b0, 0))));
            int pos = lane * 4;
            if (n0) idx_lds[wave][d][r] = pos;
            r += n0;
            if (n1) idx_lds[wave][d][r] = pos + 1;
            r += n1;
            if (n2) idx_lds[wave][d][r] = pos + 2;
            r += n2;
            if (n3) idx_lds[wave][d][r] = pos + 3;
        }
#pragma unroll
        for (int d = 0; d < 8; ++d)
            c[d] = *(const float4*)(cfg + (size_t)chunk * 4096 + (size_t)(d + 8) * 256 + (size_t)lane * 4);
#pragma unroll
        for (int d = 0; d < 8; ++d) {
            float4 v = c[d];
            bool n0 = v.x != 0.f, n1 = v.y != 0.f, n2 = v.z != 0.f, n3 = v.w != 0.f;
            unsigned long long b0 = __ballot(n0);
            unsigned long long b1 = __ballot(n1);
            unsigned long long b2 = __ballot(n2);
            unsigned long long b3 = __ballot(n3);
            int r = mbcnt64(b3, mbcnt64(b2, mbcnt64(b1, mbcnt64(b0, 0))));
            int pos = lane * 4;
            if (n0) idx_lds[wave][d + 8][r] = pos;
            r += n0;
            if (n1) idx_lds[wave][d + 8][r] = pos + 1;
            r += n1;
            if (n2) idx_lds[wave][d + 8][r] = pos + 2;
            r += n2;
            if (n3) idx_lds[wave][d + 8][r] = pos + 3;
        }
        asm volatile("s_waitcnt lgkmcnt(0)" ::: "memory");

        const int4 ri = *(const int4*)&idx_lds[wave][g][q * 4];
        const int rid[4] = {ri.x, ri.y, ri.z, ri.w};

        float rr[4][16];
#pragma unroll
        for (int j = 0; j < 4; ++j) {
            const float* p = tab + (size_t)rid[j] * 16;
            float4 a = *(const float4*)(p + 0);
            float4 b = *(const float4*)(p + 4);
            float4 e = *(const float4*)(p + 8);
            float4 f = *(const float4*)(p + 12);
            rr[j][0]=a.x;  rr[j][1]=a.y;  rr[j][2]=a.z;  rr[j][3]=a.w;
            rr[j][4]=b.x;  rr[j][5]=b.y;  rr[j][6]=b.z;  rr[j][7]=b.w;
            rr[j][8]=e.x;  rr[j][9]=e.y;  rr[j][10]=e.z; rr[j][11]=e.w;
            rr[j][12]=f.x; rr[j][13]=f.y; rr[j][14]=f.z; rr[j][15]=f.w;
        }

        if (nxt < total) {
#pragma unroll
            for (int d = 0; d < 8; ++d)
                c[d] = *(const float4*)(cfg + (size_t)chnxt * 4096 + (size_t)d * 256 + (size_t)lane * 4);
        }

        float det = 1.f;
        float minpiv = 1.f;
#pragma unroll
        for (int k = 0; k < 16; ++k) {
            const int sel = k >> 2;
            const int jp  = k & 3;
            float piv = qb(rr[jp][k], sel);
            det *= piv;
            minpiv = fminf(minpiv, fabsf(piv));
            float inv = __builtin_amdgcn_rcpf(piv);
            float f0 = rr[0][k] * inv;
            float f1 = rr[1][k] * inv;
            float f2 = rr[2][k] * inv;
            float f3 = rr[3][k] * inv;
#pragma unroll
            for (int cc = k + 1; cc < 16; ++cc) {
                float pcc = qb(rr[jp][cc], sel);
                rr[0][cc] = __builtin_fmaf(-f0, pcc, rr[0][cc]);
                rr[1][cc] = __builtin_fmaf(-f1, pcc, rr[1][cc]);
                rr[2][cc] = __builtin_fmaf(-f2, pcc, rr[2][cc]);
                rr[3][cc] = __builtin_fmaf(-f3, pcc, rr[3][cc]);
            }
        }
        bool bad = minpiv < 1e-4f;

        int badflag = bad ? 1 : 0;
        int partnerbad = __shfl_xor(badflag, 4);
        if ((badflag | partnerbad) && (lane & 7) == 0) {
            unsigned slot = atomicAdd(ws_count, 1u);
            if (slot < cap) {
                unsigned* rec = ws_rec + slot * 12;
                rec[0] = (unsigned)(chunk * 8 + (lane >> 3));
                const int gU = lane >> 2;
#pragma unroll
                for (int t = 0; t < 4; ++t) {
                    const int* iu = &idx_lds[wave][gU][t * 4];
                    const int* id = &idx_lds[wave][gU | 1][t * 4];
                    rec[1 + t] = (unsigned)iu[0] | ((unsigned)iu[1] << 8)
                               | ((unsigned)iu[2] << 16) | ((unsigned)iu[3] << 24);
                    rec[5 + t] = (unsigned)id[0] | ((unsigned)id[1] << 8)
                               | ((unsigned)id[2] << 16) | ((unsigned)id[3] << 24);
                }
            }
        }

        float prod = det * __shfl_xor(det, 4);
        if ((lane & 7) == 0) out[chunk * 8 + (lane >> 3)] = prod;

        cur = nxt;
        chunk = chnxt;
    }
}

__global__ __launch_bounds__(256) void slater_det_cleanup(
    const float* __restrict__ sup,
    const float* __restrict__ sdn,
    float* __restrict__ out,
    const unsigned* __restrict__ ws_count,
    const unsigned* __restrict__ ws_rec,
    unsigned cap)
{
    unsigned n = *ws_count;
    if (n > cap) n = cap;
    const int tid  = blockIdx.x * 256 + threadIdx.x;
    const int unit = tid >> 3;
    const int nunits = (int)(gridDim.x * 256) >> 3;
    const int l8   = threadIdx.x & 7;
    const int wl   = threadIdx.x & 63;
    const int q    = wl & 3;
    const int gbase = wl & ~3;

    for (unsigned item = unit; item < n; item += nunits) {
        const unsigned* rec = ws_rec + item * 12;
        const unsigned batch = rec[0];
        const int half = l8 >> 2;
        const unsigned pk = rec[1 + half * 4 + q];
        const int rid[4] = { (int)(pk & 255u), (int)((pk >> 8) & 255u),
                             (int)((pk >> 16) & 255u), (int)(pk >> 24) };
        const float* tab = half ? sdn : sup;

        float rr[4][16];
#pragma unroll
        for (int j = 0; j < 4; ++j) {
            const float* p = tab + (size_t)rid[j] * 16;
            float4 a = *(const float4*)(p + 0);
            float4 b = *(const float4*)(p + 4);
            float4 e = *(const float4*)(p + 8);
            float4 f = *(const float4*)(p + 12);
            rr[j][0]=a.x;  rr[j][1]=a.y;  rr[j][2]=a.z;  rr[j][3]=a.w;
            rr[j][4]=b.x;  rr[j][5]=b.y;  rr[j][6]=b.z;  rr[j][7]=b.w;
            rr[j][8]=e.x;  rr[j][9]=e.y;  rr[j][10]=e.z; rr[j][11]=e.w;
            rr[j][12]=f.x; rr[j][13]=f.y; rr[j][14]=f.z; rr[j][15]=f.w;
        }

        unsigned am = 0xFu;
        float fdet = 1.f;
        int flips = 0;
#pragma unroll
        for (int k = 0; k < 16; ++k) {
            unsigned a0 = (__float_as_uint(rr[0][k]) & 0x7FFFFFF0u) | (unsigned)(q*4+0);
            unsigned a1 = (__float_as_uint(rr[1][k]) & 0x7FFFFFF0u) | (unsigned)(q*4+1);
            unsigned a2 = (__float_as_uint(rr[2][k]) & 0x7FFFFFF0u) | (unsigned)(q*4+2);
            unsigned a3 = (__float_as_uint(rr[3][k]) & 0x7FFFFFF0u) | (unsigned)(q*4+3);
            unsigned key0 = (am & 1u) ? a0 : (unsigned)(q*4+0);
            unsigned key1 = (am & 2u) ? a1 : (unsigned)(q*4+1);
            unsigned key2 = (am & 4u) ? a2 : (unsigned)(q*4+2);
            unsigned key3 = (am & 8u) ? a3 : (unsigned)(q*4+3);
            unsigned kloc = umax2(umax2(key0, key1), umax2(key2, key3));
            int jloc = (int)(kloc & 3u);
            float crow[16];
#pragma unroll
            for (int cc = k; cc < 16; ++cc) {
                float t01 = (jloc & 1) ? rr[1][cc] : rr[0][cc];
                float t23 = (jloc & 1) ? rr[3][cc] : rr[2][cc];
                crow[cc] = (jloc & 2) ? t23 : t01;
            }
            unsigned ko = kloc;
            ko = umax2(ko, (unsigned)__shfl_xor((int)ko, 1));
            ko = umax2(ko, (unsigned)__shfl_xor((int)ko, 2));
            int p   = (int)(ko & 15u);
            int src = gbase | (p >> 2);
            float prow[16];
#pragma unroll
            for (int cc = k; cc < 16; ++cc) prow[cc] = __shfl(crow[cc], src);
            float piv = prow[k];
            fdet *= piv;
            int t = p - q * 4;
            unsigned mlt = (t <= 0) ? 0u : ((t >= 4) ? 0xFu : ((1u << t) - 1u));
            int cnt = __popc(am & mlt);
            cnt += __shfl_xor(cnt, 1);
            cnt += __shfl_xor(cnt, 2);
            flips += cnt;
            if (q == (p >> 2)) am &= ~(1u << (p & 3));
            float inv = 1.0f / piv;
            float f0 = rr[0][k] * inv;
            float f1 = rr[1][k] * inv;
            float f2 = rr[2][k] * inv;
            float f3 = rr[3][k] * inv;
#pragma unroll
            for (int cc = k + 1; cc < 16; ++cc) {
                rr[0][cc] = __builtin_fmaf(-f0, prow[cc], rr[0][cc]);
                rr[1][cc] = __builtin_fmaf(-f1, prow[cc], rr[1][cc]);
                rr[2][cc] = __builtin_fmaf(-f2, prow[cc], rr[2][cc]);
                rr[3][cc] = __builtin_fmaf(-f3, prow[cc], rr[3][cc]);
            }
        }
        float det = (flips & 1) ? -fdet : fdet;
        float prod = det * __shfl_xor(det, 4);
        if (l8 == 0) out[batch] = prod;
    }
}

extern "C" void kernel_launch(void* const* d_in, const int* in_sizes, int n_in,
                              void* d_out, int out_size, void* d_ws, size_t ws_size,
                              hipStream_t stream) {
    const float* cfg = (const float*)d_in[0];
    const float* sup = (const float*)d_in[1];
    const float* sdn = (const float*)d_in[2];
    float* outp = (float*)d_out;
    unsigned* ws_count = (unsigned*)d_ws;
    unsigned* ws_rec   = (unsigned*)d_ws + 4;
    unsigned cap = (unsigned)((ws_size - 16) / 48);
    const int B = in_sizes[0] / 512;                     // 131072
    const int nchunks = B / 8;                           // 16384 (pow2)

    hipMemsetAsync(d_ws, 0, 16, stream);
    slater_det_main<<<1024, 256, 0, stream>>>(cfg, sup, sdn, outp,
                                              ws_count, ws_rec, cap,
                                              nchunks * REPS, nchunks - 1);
    slater_det_cleanup<<<16, 256, 0, stream>>>(sup, sdn, outp,
                                               ws_count, ws_rec, cap);
}

// Round 16
// 64.512 us; speedup vs baseline: 2.8405x; 2.8405x over previous
//
#include <hip/hip_runtime.h>

static __device__ __forceinline__ unsigned umax2(unsigned a, unsigned b) { return a > b ? a : b; }

// Quad-lane broadcast via DPP quad_perm (VALU pipe, ~2cyc). sel compile-time.
static __device__ __forceinline__ float qb(float v, int sel) {
    int i = __float_as_int(v), r;
    switch (sel) {
        case 0:  r = __builtin_amdgcn_update_dpp(0, i, 0x00, 0xF, 0xF, true); break;
        case 1:  r = __builtin_amdgcn_update_dpp(0, i, 0x55, 0xF, 0xF, true); break;
        case 2:  r = __builtin_amdgcn_update_dpp(0, i, 0xAA, 0xF, 0xF, true); break;
        default: r = __builtin_amdgcn_update_dpp(0, i, 0xFF, 0xF, 0xF, true); break;
    }
    return __int_as_float(r);
}

static __device__ __forceinline__ int mbcnt64(unsigned long long m, int acc) {
    acc = __builtin_amdgcn_mbcnt_lo((unsigned)m, acc);
    acc = __builtin_amdgcn_mbcnt_hi((unsigned)(m >> 32), acc);
    return acc;
}

// ---------------------------------------------------------------------------
// R16 = R12 source byte-identical, grid 1024 -> 2048.
// R15 diagnostic showed VGPR=64 (8 waves/SIMD allowed) but Occupancy 38%:
// the 1024-block grid capped residency at 4 blocks/CU (50% occ ceiling),
// and VALUBusy 55% with L3-resident passes at ~56us proves latency/issue
// bound, not BW bound. 2048 blocks -> 8 blocks/CU -> 32 waves/CU (100%).
// ---------------------------------------------------------------------------
__global__ __launch_bounds__(256) void slater_det_main(
    const float* __restrict__ cfg,
    const float* __restrict__ sup,
    const float* __restrict__ sdn,
    float* __restrict__ out,
    unsigned* __restrict__ ws_count,
    unsigned* __restrict__ ws_rec,
    unsigned cap,
    int nchunks)
{
    __shared__ __align__(16) int idx_lds[4][16][16];

    const int tid  = threadIdx.x;
    const int wave = tid >> 6;
    const int lane = tid & 63;
    const int wgid = blockIdx.x * 4 + wave;
    const int nw   = gridDim.x * 4;

    const int g = lane >> 2;
    const int q = lane & 3;
    const float* tab = (g & 1) ? sdn : sup;

    float4 c[8];
    int cur = wgid;
    if (cur >= nchunks) return;

#pragma unroll
    for (int d = 0; d < 8; ++d)
        c[d] = *(const float4*)(cfg + (size_t)cur * 4096 + (size_t)d * 256 + (size_t)lane * 4);

    while (cur < nchunks) {
        const int nxt = cur + nw;

#pragma unroll
        for (int d = 0; d < 8; ++d) {
            float4 v = c[d];
            bool n0 = v.x != 0.f, n1 = v.y != 0.f, n2 = v.z != 0.f, n3 = v.w != 0.f;
            unsigned long long b0 = __ballot(n0);
            unsigned long long b1 = __ballot(n1);
            unsigned long long b2 = __ballot(n2);
            unsigned long long b3 = __ballot(n3);
            int r = mbcnt64(b3, mbcnt64(b2, mbcnt64(b1, mbcnt64(b0, 0))));
            int pos = lane * 4;
            if (n0) idx_lds[wave][d][r] = pos;       // exactly 16 ones: r<16 holds
            r += n0;
            if (n1) idx_lds[wave][d][r] = pos + 1;
            r += n1;
            if (n2) idx_lds[wave][d][r] = pos + 2;
            r += n2;
            if (n3) idx_lds[wave][d][r] = pos + 3;
        }
#pragma unroll
        for (int d = 0; d < 8; ++d)
            c[d] = *(const float4*)(cfg + (size_t)cur * 4096 + (size_t)(d + 8) * 256 + (size_t)lane * 4);
#pragma unroll
        for (int d = 0; d < 8; ++d) {
            float4 v = c[d];
            bool n0 = v.x != 0.f, n1 = v.y != 0.f, n2 = v.z != 0.f, n3 = v.w != 0.f;
            unsigned long long b0 = __ballot(n0);
            unsigned long long b1 = __ballot(n1);
            unsigned long long b2 = __ballot(n2);
            unsigned long long b3 = __ballot(n3);
            int r = mbcnt64(b3, mbcnt64(b2, mbcnt64(b1, mbcnt64(b0, 0))));
            int pos = lane * 4;
            if (n0) idx_lds[wave][d + 8][r] = pos;
            r += n0;
            if (n1) idx_lds[wave][d + 8][r] = pos + 1;
            r += n1;
            if (n2) idx_lds[wave][d + 8][r] = pos + 2;
            r += n2;
            if (n3) idx_lds[wave][d + 8][r] = pos + 3;
        }
        // wave-private LDS region: wave-local drain replaces __syncthreads
        asm volatile("s_waitcnt lgkmcnt(0)" ::: "memory");

        const int4 ri = *(const int4*)&idx_lds[wave][g][q * 4];
        const int rid[4] = {ri.x, ri.y, ri.z, ri.w};

        float rr[4][16];
#pragma unroll
        for (int j = 0; j < 4; ++j) {
            const float* p = tab + (size_t)rid[j] * 16;
            float4 a = *(const float4*)(p + 0);
            float4 b = *(const float4*)(p + 4);
            float4 e = *(const float4*)(p + 8);
            float4 f = *(const float4*)(p + 12);
            rr[j][0]=a.x;  rr[j][1]=a.y;  rr[j][2]=a.z;  rr[j][3]=a.w;
            rr[j][4]=b.x;  rr[j][5]=b.y;  rr[j][6]=b.z;  rr[j][7]=b.w;
            rr[j][8]=e.x;  rr[j][9]=e.y;  rr[j][10]=e.z; rr[j][11]=e.w;
            rr[j][12]=f.x; rr[j][13]=f.y; rr[j][14]=f.z; rr[j][15]=f.w;
        }

        if (nxt < nchunks) {
#pragma unroll
            for (int d = 0; d < 8; ++d)
                c[d] = *(const float4*)(cfg + (size_t)nxt * 4096 + (size_t)d * 256 + (size_t)lane * 4);
        }

        float det = 1.f;
        float minpiv = 1.f;
#pragma unroll
        for (int k = 0; k < 16; ++k) {
            const int sel = k >> 2;
            const int jp  = k & 3;
            float piv = qb(rr[jp][k], sel);
            det *= piv;
            minpiv = fminf(minpiv, fabsf(piv));
            float inv = __builtin_amdgcn_rcpf(piv);
            float f0 = rr[0][k] * inv;
            float f1 = rr[1][k] * inv;
            float f2 = rr[2][k] * inv;
            float f3 = rr[3][k] * inv;
#pragma unroll
            for (int cc = k + 1; cc < 16; ++cc) {
                float pcc = qb(rr[jp][cc], sel);
                rr[0][cc] = __builtin_fmaf(-f0, pcc, rr[0][cc]);
                rr[1][cc] = __builtin_fmaf(-f1, pcc, rr[1][cc]);
                rr[2][cc] = __builtin_fmaf(-f2, pcc, rr[2][cc]);
                rr[3][cc] = __builtin_fmaf(-f3, pcc, rr[3][cc]);
            }
        }
        bool bad = minpiv < 1e-4f;

        int badflag = bad ? 1 : 0;
        int partnerbad = __shfl_xor(badflag, 4);
        if ((badflag | partnerbad) && (lane & 7) == 0) {
            unsigned slot = atomicAdd(ws_count, 1u);
            if (slot < cap) {
                unsigned* rec = ws_rec + slot * 12;
                rec[0] = (unsigned)(cur * 8 + (lane >> 3));
                const int gU = lane >> 2;              // even quad (up half)
#pragma unroll
                for (int t = 0; t < 4; ++t) {
                    const int* iu = &idx_lds[wave][gU][t * 4];
                    const int* id = &idx_lds[wave][gU | 1][t * 4];
                    rec[1 + t] = (unsigned)iu[0] | ((unsigned)iu[1] << 8)
                               | ((unsigned)iu[2] << 16) | ((unsigned)iu[3] << 24);
                    rec[5 + t] = (unsigned)id[0] | ((unsigned)id[1] << 8)
                               | ((unsigned)id[2] << 16) | ((unsigned)id[3] << 24);
                }
            }
        }

        float prod = det * __shfl_xor(det, 4);
        if ((lane & 7) == 0) out[cur * 8 + (lane >> 3)] = prod;

        cur = nxt;
    }
}

// ---------------------------------------------------------------------------
// Cleanup kernel: 8 lanes per batch, full partial pivoting. Rare (~0.1%).
// ---------------------------------------------------------------------------
__global__ __launch_bounds__(256) void slater_det_cleanup(
    const float* __restrict__ sup,
    const float* __restrict__ sdn,
    float* __restrict__ out,
    const unsigned* __restrict__ ws_count,
    const unsigned* __restrict__ ws_rec,
    unsigned cap)
{
    unsigned n = *ws_count;
    if (n > cap) n = cap;
    const int tid  = blockIdx.x * 256 + threadIdx.x;
    const int unit = tid >> 3;
    const int nunits = (int)(gridDim.x * 256) >> 3;
    const int l8   = threadIdx.x & 7;
    const int wl   = threadIdx.x & 63;
    const int q    = wl & 3;
    const int gbase = wl & ~3;

    for (unsigned item = unit; item < n; item += nunits) {
        const unsigned* rec = ws_rec + item * 12;
        const unsigned batch = rec[0];
        const int half = l8 >> 2;
        const unsigned pk = rec[1 + half * 4 + q];
        const int rid[4] = { (int)(pk & 255u), (int)((pk >> 8) & 255u),
                             (int)((pk >> 16) & 255u), (int)(pk >> 24) };
        const float* tab = half ? sdn : sup;

        float rr[4][16];
#pragma unroll
        for (int j = 0; j < 4; ++j) {
            const float* p = tab + (size_t)rid[j] * 16;
            float4 a = *(const float4*)(p + 0);
            float4 b = *(const float4*)(p + 4);
            float4 e = *(const float4*)(p + 8);
            float4 f = *(const float4*)(p + 12);
            rr[j][0]=a.x;  rr[j][1]=a.y;  rr[j][2]=a.z;  rr[j][3]=a.w;
            rr[j][4]=b.x;  rr[j][5]=b.y;  rr[j][6]=b.z;  rr[j][7]=b.w;
            rr[j][8]=e.x;  rr[j][9]=e.y;  rr[j][10]=e.z; rr[j][11]=e.w;
            rr[j][12]=f.x; rr[j][13]=f.y; rr[j][14]=f.z; rr[j][15]=f.w;
        }

        unsigned am = 0xFu;
        float fdet = 1.f;
        int flips = 0;
#pragma unroll
        for (int k = 0; k < 16; ++k) {
            unsigned a0 = (__float_as_uint(rr[0][k]) & 0x7FFFFFF0u) | (unsigned)(q*4+0);
            unsigned a1 = (__float_as_uint(rr[1][k]) & 0x7FFFFFF0u) | (unsigned)(q*4+1);
            unsigned a2 = (__float_as_uint(rr[2][k]) & 0x7FFFFFF0u) | (unsigned)(q*4+2);
            unsigned a3 = (__float_as_uint(rr[3][k]) & 0x7FFFFFF0u) | (unsigned)(q*4+3);
            unsigned key0 = (am & 1u) ? a0 : (unsigned)(q*4+0);
            unsigned key1 = (am & 2u) ? a1 : (unsigned)(q*4+1);
            unsigned key2 = (am & 4u) ? a2 : (unsigned)(q*4+2);
            unsigned key3 = (am & 8u) ? a3 : (unsigned)(q*4+3);
            unsigned kloc = umax2(umax2(key0, key1), umax2(key2, key3));
            int jloc = (int)(kloc & 3u);
            float crow[16];
#pragma unroll
            for (int cc = k; cc < 16; ++cc) {
                float t01 = (jloc & 1) ? rr[1][cc] : rr[0][cc];
                float t23 = (jloc & 1) ? rr[3][cc] : rr[2][cc];
                crow[cc] = (jloc & 2) ? t23 : t01;
            }
            unsigned ko = kloc;
            ko = umax2(ko, (unsigned)__shfl_xor((int)ko, 1));
            ko = umax2(ko, (unsigned)__shfl_xor((int)ko, 2));
            int p   = (int)(ko & 15u);
            int src = gbase | (p >> 2);
            float prow[16];
#pragma unroll
            for (int cc = k; cc < 16; ++cc) prow[cc] = __shfl(crow[cc], src);
            float piv = prow[k];
            fdet *= piv;
            int t = p - q * 4;
            unsigned mlt = (t <= 0) ? 0u : ((t >= 4) ? 0xFu : ((1u << t) - 1u));
            int cnt = __popc(am & mlt);
            cnt += __shfl_xor(cnt, 1);
            cnt += __shfl_xor(cnt, 2);
            flips += cnt;
            if (q == (p >> 2)) am &= ~(1u << (p & 3));
            float inv = 1.0f / piv;
            float f0 = rr[0][k] * inv;
            float f1 = rr[1][k] * inv;
            float f2 = rr[2][k] * inv;
            float f3 = rr[3][k] * inv;
#pragma unroll
            for (int cc = k + 1; cc < 16; ++cc) {
                rr[0][cc] = __builtin_fmaf(-f0, prow[cc], rr[0][cc]);
                rr[1][cc] = __builtin_fmaf(-f1, prow[cc], rr[1][cc]);
                rr[2][cc] = __builtin_fmaf(-f2, prow[cc], rr[2][cc]);
                rr[3][cc] = __builtin_fmaf(-f3, prow[cc], rr[3][cc]);
            }
        }
        float det = (flips & 1) ? -fdet : fdet;
        float prod = det * __shfl_xor(det, 4);
        if (l8 == 0) out[batch] = prod;
    }
}

extern "C" void kernel_launch(void* const* d_in, const int* in_sizes, int n_in,
                              void* d_out, int out_size, void* d_ws, size_t ws_size,
                              hipStream_t stream) {
    const float* cfg = (const float*)d_in[0];
    const float* sup = (const float*)d_in[1];
    const float* sdn = (const float*)d_in[2];
    float* outp = (float*)d_out;
    unsigned* ws_count = (unsigned*)d_ws;
    unsigned* ws_rec   = (unsigned*)d_ws + 4;            // records at +16B
    unsigned cap = (unsigned)((ws_size - 16) / 48);      // 12 uints per record
    const int B = in_sizes[0] / 512;                     // 131072
    const int nchunks = B / 8;                           // 16384

    hipMemsetAsync(d_ws, 0, 16, stream);
    slater_det_main<<<2048, 256, 0, stream>>>(cfg, sup, sdn, outp,
                                              ws_count, ws_rec, cap, nchunks);
    slater_det_cleanup<<<16, 256, 0, stream>>>(sup, sdn, outp,
                                               ws_count, ws_rec, cap);
}